// Round 5
// baseline (375.559 us; speedup 1.0000x reference)
//
#include <hip/hip_runtime.h>

#define N_NODES 50000
#define N_EDGES 800000
#define IN_F    128
#define OUT_F   128
#define NEIG    64
#define HDIM    128
#define BN_EPSF 1e-5f
#define XB_ROWS 50048            // 50000 padded to 128
#define XB_COLS 640
#define SCAN_BLK 49              // ceil(50000/1024)
#define HSP_BLOCKS 521           // 521*96 >= 50000
#define HSP_NODES 96
#define RED_CHUNK 33             // ceil(521/16)
#define N_CHK 16                 // edge chunks (replica dim for rank merge)
#define N_RNG 4                  // node ranges (12500 nodes -> 25KB LDS counters)
#define RANKB (N_RNG * N_CHK)    // 64 rank blocks

typedef __attribute__((ext_vector_type(8))) short short8;
typedef __attribute__((ext_vector_type(4))) float floatx4;

// ---- workspace layout (in 4-byte units) ----
#define OFF_XB      0                                   // ushort[50048*640]
#define OFF_X1F     (XB_ROWS * XB_COLS / 2)             // hs partials region
#define OFF_X2F     (OFF_X1F + N_NODES * IN_F)          // degC/rsC live here (25.6MB free)
#define OFF_DEGC    OFF_X2F                             // int[16*N] per-chunk counts
#define OFF_RSC     (OFF_X2F + N_CHK * N_NODES)         // int[16*N] chunk scatter bases
#define OFF_WT      (OFF_X2F + N_NODES * IN_F)          // ushort[640*128]
#define OFF_DSQRT   (OFF_WT + 40960)
#define OFF_HS      (OFF_DSQRT + N_NODES)
#define OFF_EF      (OFF_HS + NEIG * OUT_F)
#define OFF_COLSUM  (OFF_EF + NEIG)
#define OFF_COLSQ   (OFF_COLSUM + OUT_F)
#define OFF_DEG     (OFF_COLSQ + OUT_F)                 // (legacy, unused)
#define OFF_ROWSTART (OFF_DEG + 8 * N_NODES)
#define OFF_CSR     (OFF_ROWSTART + N_NODES + 1)
#define OFF_BSUM    (OFF_CSR + N_EDGES)                 // 64 ints
#define OFF_RANK    (OFF_BSUM + 64)                     // E ints
// end ~= 29.4M * 4B ~= 118 MB (< 128.3 MB proven in R0)

static __device__ inline unsigned short f2bf(float f) {
    union { float f; unsigned int u; } v; v.f = f;
    unsigned int r = (v.u + 0x7FFFu + ((v.u >> 16) & 1u)) >> 16;
    return (unsigned short)r;
}
static __device__ inline float bf2f(unsigned int u16) {
    union { unsigned int u; float f; } v; v.u = u16 << 16;
    return v.f;
}

// merged: feat2bf (blocks 0..3124) | wt (3125..3444) | zero stats (3445..3478)
__global__ __launch_bounds__(256) void k_prep(const float* __restrict__ feat,
                                              const float* __restrict__ W,
                                              unsigned short* __restrict__ Xb,
                                              unsigned short* __restrict__ Wt,
                                              float* __restrict__ small) {
    int b = blockIdx.x;
    if (b < 3125) {
        int t = b * 256 + threadIdx.x;           // [0, 800000)
        int n = t >> 4, c8 = (t & 15) * 8;
        float4 a = *(const float4*)&feat[n * IN_F + c8];
        float4 bb = *(const float4*)&feat[n * IN_F + c8 + 4];
        ushort4 o0, o1;
        o0.x = f2bf(a.x); o0.y = f2bf(a.y); o0.z = f2bf(a.z); o0.w = f2bf(a.w);
        o1.x = f2bf(bb.x); o1.y = f2bf(bb.y); o1.z = f2bf(bb.z); o1.w = f2bf(bb.w);
        *(ushort4*)&Xb[(size_t)n * XB_COLS + c8]     = o0;
        *(ushort4*)&Xb[(size_t)n * XB_COLS + c8 + 4] = o1;
    } else if (b < 3445) {
        int t = (b - 3125) * 256 + threadIdx.x;  // [0, 81920)
        int k = t >> 7, n = t & 127;
        Wt[n * 640 + k] = f2bf(W[k * 128 + n]);
    } else {
        int i = (b - 3445) * 256 + threadIdx.x;
        if (i < NEIG * OUT_F + NEIG + 2 * OUT_F) small[i] = 0.0f;
    }
}

// fused: hs_partial (0..520) | eigen-MLP x2 (521..552) | LDS-rank (553..616)
// rank: ZERO device atomics (R0-R4 proved 800K memory-side RMWs = fixed ~40us toll:
// WRITE_SIZE 28MB write-through; conflicts/ILP/XCD-locality all null). Block (g,c)
// LDS-counts chunk c's dsts in node range g (12500 packed-u16 counters = 25KB),
// emits per-(dst,chunk) local ranks + per-chunk counts; scan merges 16 chunks.
__global__ __launch_bounds__(256) void k_stage2(const float* __restrict__ evecs,
                                                const float* __restrict__ feat,
                                                float* __restrict__ partials,
                                                const float* __restrict__ evals,
                                                const float* __restrict__ ew0,
                                                const float* __restrict__ eb0,
                                                const float* __restrict__ ew1,
                                                const float* __restrict__ eb1,
                                                const float* __restrict__ ew2,
                                                const float* __restrict__ eb2,
                                                float* __restrict__ ef,
                                                int* __restrict__ degC,
                                                const int* __restrict__ dst,
                                                int* __restrict__ rank) {
    int b = blockIdx.x;
    int t = threadIdx.x;
    if (b < HSP_BLOCKS) {
        // ---- hs partial: block handles 96 nodes; partial C[64][128] -> partials[b]
        __shared__ float sEv[32 * NEIG];    // 8 KB
        __shared__ float sFt[32 * IN_F];    // 16 KB
        int e0 = (t >> 5) * 8;
        int f0 = (t & 31) * 4;
        float acc[8][4];
#pragma unroll
        for (int r = 0; r < 8; ++r)
#pragma unroll
            for (int c = 0; c < 4; ++c) acc[r][c] = 0.0f;

        int n0 = b * HSP_NODES;
        for (int ch = 0; ch < HSP_NODES; ch += 32) {
            int base = n0 + ch;
            {
                int r = t >> 3, c = (t & 7) * 8;
                int n = base + r;
                float4 a, bb;
                if (n < N_NODES) {
                    a = *(const float4*)&evecs[(size_t)n * NEIG + c];
                    bb = *(const float4*)&evecs[(size_t)n * NEIG + c + 4];
                } else {
                    a = make_float4(0, 0, 0, 0); bb = a;
                }
                *(float4*)&sEv[r * NEIG + c] = a;
                *(float4*)&sEv[r * NEIG + c + 4] = bb;
            }
            {
                int r = t >> 3, c = (t & 7) * 16;
                int n = base + r;
#pragma unroll
                for (int q = 0; q < 4; ++q) {
                    float4 v = (n < N_NODES) ? *(const float4*)&feat[(size_t)n * IN_F + c + q * 4]
                                             : make_float4(0, 0, 0, 0);
                    *(float4*)&sFt[r * IN_F + c + q * 4] = v;
                }
            }
            __syncthreads();
#pragma unroll 2
            for (int i = 0; i < 32; ++i) {
                float4 ev0 = *(float4*)&sEv[i * NEIG + e0];
                float4 ev1 = *(float4*)&sEv[i * NEIG + e0 + 4];
                float4 fv  = *(float4*)&sFt[i * IN_F + f0];
                float evv[8] = {ev0.x, ev0.y, ev0.z, ev0.w, ev1.x, ev1.y, ev1.z, ev1.w};
#pragma unroll
                for (int r = 0; r < 8; ++r) {
                    acc[r][0] += evv[r] * fv.x;
                    acc[r][1] += evv[r] * fv.y;
                    acc[r][2] += evv[r] * fv.z;
                    acc[r][3] += evv[r] * fv.w;
                }
            }
            __syncthreads();
        }
        float* p = &partials[(size_t)b * (NEIG * IN_F)];
#pragma unroll
        for (int r = 0; r < 8; ++r)
            *(float4*)&p[(e0 + r) * IN_F + f0] = make_float4(acc[r][0], acc[r][1], acc[r][2], acc[r][3]);
    } else if (b < HSP_BLOCKS + 32) {
        // ---- eigen-MLP: 2 eigenvalues per 256-thread block
        __shared__ float z0[2][HDIM];
        __shared__ float red[2][HDIM];
        int sub = t >> 7, j = t & 127;
        int i = (b - HSP_BLOCKS) * 2 + sub;
        float ev = evals[i];
        z0[sub][j] = fmaxf(0.0f, ev * ew0[j] + eb0[j]);
        __syncthreads();
        float s0 = 0.f, s1 = 0.f, s2 = 0.f, s3 = 0.f;
        for (int h = 0; h < HDIM; h += 4) {
            s0 += z0[sub][h]     * ew1[(h) * HDIM + j];
            s1 += z0[sub][h + 1] * ew1[(h + 1) * HDIM + j];
            s2 += z0[sub][h + 2] * ew1[(h + 2) * HDIM + j];
            s3 += z0[sub][h + 3] * ew1[(h + 3) * HDIM + j];
        }
        float z1 = fmaxf(0.0f, eb1[j] + s0 + s1 + s2 + s3);
        red[sub][j] = z1 * ew2[j];
        __syncthreads();
        for (int off = 64; off > 0; off >>= 1) {
            if (j < off) red[sub][j] += red[sub][j + off];
            __syncthreads();
        }
        if (j == 0) ef[i] = red[sub][0] + eb2[0];
    } else {
        // ---- LDS rank: block (g,c); g = node range [g*12500, +12500), c = edge chunk
        __shared__ unsigned int cnt[6250];      // 12500 u16 counters packed, 25 KB
        int rb = b - (HSP_BLOCKS + 32);
        int g = rb >> 4, c = rb & (N_CHK - 1);
        for (int k = t; k < 6250; k += 256) cnt[k] = 0;
        __syncthreads();
        int nlo = g * 12500;
        int ebase = c * 50000;
        for (int off = t; off < 50000; off += 256) {
            int e = ebase + off;
            int d = dst[e];
            int l = d - nlo;
            if ((unsigned)l < 12500u) {
                unsigned sh = (l & 1) * 16;
                unsigned old = atomicAdd(&cnt[l >> 1], 1u << sh);
                int lrank = (old >> sh) & 0xFFFF;
                rank[e] = lrank | (c << 24);
            }
        }
        __syncthreads();
        // per-chunk counts for this range (each (c,node) written exactly once)
        for (int k = t; k < 6250; k += 256) {
            unsigned v = cnt[k];
            int n0 = nlo + k * 2;
            degC[(size_t)c * N_NODES + n0]     = (int)(v & 0xFFFF);
            degC[(size_t)c * N_NODES + n0 + 1] = (int)(v >> 16);
        }
    }
}

// fused: scan1 (blocks 0..48) | hs_reduce (49..176), 1024 threads
__global__ __launch_bounds__(1024) void k_stage3(int* __restrict__ degC,
                                                 int* __restrict__ row_start,
                                                 int* __restrict__ bsum,
                                                 const float* __restrict__ partials,
                                                 float* __restrict__ hs_small) {
    int b = blockIdx.x;
    int t = threadIdx.x;
    if (b < SCAN_BLK) {
        __shared__ int sd[1024];
        int i = b * 1024 + t;
        int d[N_CHK];
#pragma unroll
        for (int cc = 0; cc < N_CHK; ++cc)
            d[cc] = (i < N_NODES) ? degC[(size_t)cc * N_NODES + i] : 0;
        int total = 0;
#pragma unroll
        for (int cc = 0; cc < N_CHK; ++cc) total += d[cc];
        sd[t] = total;
        __syncthreads();
        for (int off = 1; off < 1024; off <<= 1) {
            int v = (t >= off) ? sd[t - off] : 0;
            __syncthreads();
            sd[t] += v;
            __syncthreads();
        }
        if (i < N_NODES) {
            row_start[i] = sd[t] - total;
            // repurpose degC: slot0 = total degree, slot c = prefix offset of chunk c
            degC[i] = total;
            int p = d[0];
#pragma unroll
            for (int cc = 1; cc < N_CHK; ++cc) {
                degC[(size_t)cc * N_NODES + i] = p;
                p += d[cc];
            }
        }
        if (t == 1023) bsum[b] = sd[1023];
    } else {
        // split reduce: 8 elem-groups x 16 j-chunks; atomicAdd into pre-zeroed hs_small
        int b2 = b - SCAN_BLK;
        int grp = b2 & 7;
        int chunk = b2 >> 3;
        int idx = grp * 1024 + t;
        int j0 = chunk * RED_CHUNK;
        int j1 = min(j0 + RED_CHUNK, HSP_BLOCKS);
        float s = 0.0f;
        for (int j = j0; j < j1; ++j) s += partials[(size_t)j * (NEIG * IN_F) + idx];
        atomicAdd(&hs_small[idx], s);
    }
}

// scan3 with inlined scan2: each block redundantly wave-prefixes the 49 bsum totals
__global__ __launch_bounds__(1024) void k_scan3(const int* __restrict__ degC,
                                                int* __restrict__ row_start,
                                                const int* __restrict__ bsum,
                                                float* __restrict__ dsq,
                                                int* __restrict__ rsC) {
    __shared__ int sOff;
    int t = threadIdx.x;
    if (t < 64) {
        int orig = (t < SCAN_BLK) ? bsum[t] : 0;
        int v = orig;
        for (int off = 1; off < 64; off <<= 1) {
            int u = __shfl_up(v, off);
            if (t >= off) v += u;
        }
        if (t == blockIdx.x) sOff = v - orig;   // exclusive prefix for this block
    }
    __syncthreads();
    int i = blockIdx.x * 1024 + t;
    if (i < N_NODES) {
        int r = row_start[i] + sOff;
        row_start[i] = r;
        rsC[i] = r;
#pragma unroll
        for (int cc = 1; cc < N_CHK; ++cc)
            rsC[(size_t)cc * N_NODES + i] = r + degC[(size_t)cc * N_NODES + i];
        dsq[i] = rsqrtf((float)max(degC[i], 1));
    }
    if (i == 0) row_start[N_NODES] = N_EDGES;
}

// fused: csr scatter (blocks 0..3124) | hs_apply (3125..4687)
__global__ __launch_bounds__(256) void k_stage6(const int* __restrict__ src,
                                                const int* __restrict__ dst,
                                                const int* __restrict__ rank,
                                                const int* __restrict__ rsC,
                                                int* __restrict__ csr_src,
                                                unsigned short* __restrict__ Xb,
                                                const float* __restrict__ evecs,
                                                const float* __restrict__ hs_small,
                                                const float* __restrict__ ef) {
    int b = blockIdx.x;
    int t = threadIdx.x;
    if (b < 3125) {
        int e = b * 256 + t;
        if (e < N_EDGES) {
            int rv = rank[e];
            int c = rv >> 24;
            csr_src[rsC[(size_t)c * N_NODES + dst[e]] + (rv & 0xFFFFFF)] = src[e];
        }
    } else {
        __shared__ float sShs[NEIG * HDIM];
        __shared__ float sEv[32 * NEIG];
        int n0 = (b - 3125) * 32;
        {
            float efv = ef[t >> 2];
            int pbase = t * 32;
#pragma unroll
            for (int q = 0; q < 8; ++q) {
                float4 v = *(const float4*)&hs_small[pbase + q * 4];
                v.x *= efv; v.y *= efv; v.z *= efv; v.w *= efv;
                *(float4*)&sShs[pbase + q * 4] = v;
            }
        }
        {
            int r = t >> 3, c = (t & 7) * 8;
            int n = n0 + r;
            float4 a, bb;
            if (n < N_NODES) {
                a = *(const float4*)&evecs[(size_t)n * NEIG + c];
                bb = *(const float4*)&evecs[(size_t)n * NEIG + c + 4];
            } else {
                a = make_float4(0, 0, 0, 0); bb = a;
            }
            *(float4*)&sEv[r * NEIG + c] = a;
            *(float4*)&sEv[r * NEIG + c + 4] = bb;
        }
        __syncthreads();
        int nb = (t >> 5) * 4;
        int f0 = (t & 31) * 4;
        float acc[4][4];
#pragma unroll
        for (int q = 0; q < 4; ++q)
#pragma unroll
            for (int c = 0; c < 4; ++c) acc[q][c] = 0.0f;
        for (int e = 0; e < NEIG; ++e) {
            float4 sv = *(float4*)&sShs[e * HDIM + f0];
#pragma unroll
            for (int q = 0; q < 4; ++q) {
                float evv = sEv[(nb + q) * NEIG + e];
                acc[q][0] += evv * sv.x;
                acc[q][1] += evv * sv.y;
                acc[q][2] += evv * sv.z;
                acc[q][3] += evv * sv.w;
            }
        }
#pragma unroll
        for (int q = 0; q < 4; ++q) {
            int n = n0 + nb + q;
            if (n < N_NODES) {
                ushort4 o;
                o.x = f2bf(acc[q][0]); o.y = f2bf(acc[q][1]);
                o.z = f2bf(acc[q][2]); o.w = f2bf(acc[q][3]);
                *(ushort4*)&Xb[(size_t)n * XB_COLS + 4 * IN_F + f0] = o;
            }
        }
    }
}

// One wave per node, all-bf16 state. 16x/8x/4x unrolled edge loop: up to 16
// independent 256 B row-loads in flight per wave. R2 LESSON: do NOT restructure
// into wider per-lane loads + lane-split — it demotes the unrolled arrays to
// scratch (VGPR 20, WRITE_SIZE 206MB) and runs 7x slower. This form is proven
// register-resident at ~40us/launch.
__global__ __launch_bounds__(256) void k_gather(const int* __restrict__ row_start,
                                                const int* __restrict__ csr_src,
                                                const float* __restrict__ dsq,
                                                const unsigned short* __restrict__ srcb,
                                                const unsigned short* __restrict__ prevb,
                                                const unsigned short* __restrict__ ppb,
                                                unsigned short* __restrict__ outb,
                                                const float* __restrict__ lm, int first) {
    int n = (blockIdx.x * 256 + threadIdx.x) >> 6;
    int lane = threadIdx.x & 63;
    if (n >= N_NODES) return;
    float rn = 2.0f / lm[0];
    float ax = 0.0f, ay = 0.0f;
    int beg = row_start[n], end = row_start[n + 1];
    int i = beg;
    for (; i + 16 <= end; i += 16) {
        int s[16]; float c[16]; unsigned int p[16];
#pragma unroll
        for (int j = 0; j < 16; ++j) s[j] = __builtin_amdgcn_readfirstlane(csr_src[i + j]);
#pragma unroll
        for (int j = 0; j < 16; ++j) c[j] = dsq[s[j]];
#pragma unroll
        for (int j = 0; j < 16; ++j)
            p[j] = *(const unsigned int*)&srcb[(size_t)s[j] * XB_COLS + lane * 2];
#pragma unroll
        for (int j = 0; j < 16; ++j) {
            ax += c[j] * bf2f(p[j] & 0xffffu);
            ay += c[j] * bf2f(p[j] >> 16);
        }
    }
    for (; i + 8 <= end; i += 8) {
        int s[8]; float c[8]; unsigned int p[8];
#pragma unroll
        for (int j = 0; j < 8; ++j) s[j] = __builtin_amdgcn_readfirstlane(csr_src[i + j]);
#pragma unroll
        for (int j = 0; j < 8; ++j) c[j] = dsq[s[j]];
#pragma unroll
        for (int j = 0; j < 8; ++j)
            p[j] = *(const unsigned int*)&srcb[(size_t)s[j] * XB_COLS + lane * 2];
#pragma unroll
        for (int j = 0; j < 8; ++j) {
            ax += c[j] * bf2f(p[j] & 0xffffu);
            ay += c[j] * bf2f(p[j] >> 16);
        }
    }
    for (; i + 4 <= end; i += 4) {
        int s[4]; float c[4]; unsigned int p[4];
#pragma unroll
        for (int j = 0; j < 4; ++j) s[j] = __builtin_amdgcn_readfirstlane(csr_src[i + j]);
#pragma unroll
        for (int j = 0; j < 4; ++j) c[j] = dsq[s[j]];
#pragma unroll
        for (int j = 0; j < 4; ++j)
            p[j] = *(const unsigned int*)&srcb[(size_t)s[j] * XB_COLS + lane * 2];
#pragma unroll
        for (int j = 0; j < 4; ++j) {
            ax += c[j] * bf2f(p[j] & 0xffffu);
            ay += c[j] * bf2f(p[j] >> 16);
        }
    }
    for (; i < end; ++i) {
        int s = __builtin_amdgcn_readfirstlane(csr_src[i]);
        float sc = dsq[s];
        unsigned int pv = *(const unsigned int*)&srcb[(size_t)s * XB_COLS + lane * 2];
        ax += sc * bf2f(pv & 0xffffu);
        ay += sc * bf2f(pv >> 16);
    }
    float ds = dsq[n];
    float a = (first ? -rn : -2.0f * rn) * ds;
    float b = first ? (rn - 1.0f) : 2.0f * (rn - 1.0f);
    unsigned int pu = *(const unsigned int*)&prevb[(size_t)n * XB_COLS + lane * 2];
    float rx = a * ax + b * bf2f(pu & 0xffffu);
    float ry = a * ay + b * bf2f(pu >> 16);
    if (ppb) {
        unsigned int qu = *(const unsigned int*)&ppb[(size_t)n * XB_COLS + lane * 2];
        rx -= bf2f(qu & 0xffffu);
        ry -= bf2f(qu >> 16);
    }
    unsigned int packed = (unsigned int)f2bf(rx) | ((unsigned int)f2bf(ry) << 16);
    *(unsigned int*)&outb[(size_t)n * XB_COLS + lane * 2] = packed;
}

// MFMA bf16 GEMM with fused BN column-stats (shfl + per-wave LDS, no LDS atomics)
__global__ __launch_bounds__(256) void k_gemm(const unsigned short* __restrict__ Xb,
                                              const unsigned short* __restrict__ Wt,
                                              const float* __restrict__ bias,
                                              float* __restrict__ out,
                                              float* __restrict__ colsum,
                                              float* __restrict__ colsq) {
    __shared__ unsigned short sA[128 * 32];
    __shared__ unsigned short sB[128 * 32];
    __shared__ float cs[4][OUT_F];
    __shared__ float cq[4][OUT_F];
    int tid = threadIdx.x;
    int wave = tid >> 6, lane = tid & 63;
    int quad = lane >> 4, m16 = lane & 15;
    int row0 = blockIdx.x * 128;

    floatx4 acc[2][8];
#pragma unroll
    for (int mt = 0; mt < 2; ++mt)
#pragma unroll
        for (int nt = 0; nt < 8; ++nt) acc[mt][nt] = (floatx4)(0.0f);

    int r  = tid >> 2;
    int c8 = (tid & 3) * 8;
    int gr0 = min(row0 + r, N_NODES - 1);
    int gr1 = min(row0 + r + 64, N_NODES - 1);

    for (int k0 = 0; k0 < 640; k0 += 32) {
        *(uint4*)&sA[r * 32 + c8]        = *(const uint4*)&Xb[(size_t)gr0 * XB_COLS + k0 + c8];
        *(uint4*)&sA[(r + 64) * 32 + c8] = *(const uint4*)&Xb[(size_t)gr1 * XB_COLS + k0 + c8];
        *(uint4*)&sB[r * 32 + c8]        = *(const uint4*)&Wt[r * 640 + k0 + c8];
        *(uint4*)&sB[(r + 64) * 32 + c8] = *(const uint4*)&Wt[(r + 64) * 640 + k0 + c8];
        __syncthreads();
        short8 a0 = *(short8*)&sA[(wave * 32 + m16) * 32 + quad * 8];
        short8 a1 = *(short8*)&sA[(wave * 32 + 16 + m16) * 32 + quad * 8];
#pragma unroll
        for (int nt = 0; nt < 8; ++nt) {
            short8 b = *(short8*)&sB[(nt * 16 + m16) * 32 + quad * 8];
            acc[0][nt] = __builtin_amdgcn_mfma_f32_16x16x32_bf16(a0, b, acc[0][nt], 0, 0, 0);
            acc[1][nt] = __builtin_amdgcn_mfma_f32_16x16x32_bf16(a1, b, acc[1][nt], 0, 0, 0);
        }
        __syncthreads();
    }
#pragma unroll
    for (int nt = 0; nt < 8; ++nt) {
        int col = nt * 16 + m16;
        float bb = bias[col];
        float sv = 0.0f, sq = 0.0f;
#pragma unroll
        for (int mt = 0; mt < 2; ++mt) {
            int rbase = row0 + wave * 32 + mt * 16 + quad * 4;
#pragma unroll
            for (int reg = 0; reg < 4; ++reg) {
                int row = rbase + reg;
                if (row < N_NODES) {
                    float w = acc[mt][nt][reg] + bb;
                    out[(size_t)row * OUT_F + col] = w;
                    sv += w;
                    sq += w * w;
                }
            }
        }
        sv += __shfl_down(sv, 32); sq += __shfl_down(sq, 32);
        sv += __shfl_down(sv, 16); sq += __shfl_down(sq, 16);
        if (lane < 16) { cs[wave][col] = sv; cq[wave][col] = sq; }
    }
    __syncthreads();
    if (tid < OUT_F) {
        float s = cs[0][tid] + cs[1][tid] + cs[2][tid] + cs[3][tid];
        float q = cq[0][tid] + cq[1][tid] + cq[2][tid] + cq[3][tid];
        atomicAdd(&colsum[tid], s);
        atomicAdd(&colsq[tid], q);
    }
}

__global__ void k_bn_apply(float* __restrict__ out, const float* __restrict__ colsum,
                           const float* __restrict__ colsq, const float* __restrict__ gamma,
                           const float* __restrict__ beta) {
    int t = blockIdx.x * 256 + threadIdx.x;
    int n = t >> 5, c = t & 31;
    float4 v = *(float4*)&out[n * OUT_F + c * 4];
    float4 s = *(const float4*)&colsum[c * 4];
    float4 q = *(const float4*)&colsq[c * 4];
    float4 g = *(const float4*)&gamma[c * 4];
    float4 b = *(const float4*)&beta[c * 4];
    const float invN = 1.0f / (float)N_NODES;
    float mux = s.x * invN, muy = s.y * invN, muz = s.z * invN, muw = s.w * invN;
    float ix = rsqrtf(q.x * invN - mux * mux + BN_EPSF);
    float iy = rsqrtf(q.y * invN - muy * muy + BN_EPSF);
    float iz = rsqrtf(q.z * invN - muz * muz + BN_EPSF);
    float iw = rsqrtf(q.w * invN - muw * muw + BN_EPSF);
    v.x = fmaxf(0.0f, (v.x - mux) * ix * g.x + b.x);
    v.y = fmaxf(0.0f, (v.y - muy) * iy * g.y + b.y);
    v.z = fmaxf(0.0f, (v.z - muz) * iz * g.z + b.z);
    v.w = fmaxf(0.0f, (v.w - muw) * iw * g.w + b.w);
    *(float4*)&out[n * OUT_F + c * 4] = v;
}

extern "C" void kernel_launch(void* const* d_in, const int* in_sizes, int n_in,
                              void* d_out, int out_size, void* d_ws, size_t ws_size,
                              hipStream_t stream) {
    const float* feature    = (const float*)d_in[0];
    const float* lin_w      = (const float*)d_in[1];
    const float* lin_b      = (const float*)d_in[2];
    const float* ew0        = (const float*)d_in[3];
    const float* eb0        = (const float*)d_in[4];
    const float* ew1        = (const float*)d_in[5];
    const float* eb1        = (const float*)d_in[6];
    const float* ew2        = (const float*)d_in[7];
    const float* eb2        = (const float*)d_in[8];
    const float* bn_gamma   = (const float*)d_in[9];
    const float* bn_beta    = (const float*)d_in[10];
    const float* lambda_max = (const float*)d_in[11];
    const float* evecs      = (const float*)d_in[12];
    const float* evals      = (const float*)d_in[13];
    const int*   edge_src   = (const int*)d_in[14];
    const int*   edge_dst   = (const int*)d_in[15];

    float* out = (float*)d_out;
    float* ws  = (float*)d_ws;
    unsigned short* Xb = (unsigned short*)(ws + OFF_XB);
    unsigned short* Wt = (unsigned short*)(ws + OFF_WT);
    float* dsq      = ws + OFF_DSQRT;
    float* hs_small = ws + OFF_HS;
    float* ef       = ws + OFF_EF;
    float* colsum   = ws + OFF_COLSUM;
    float* colsq    = ws + OFF_COLSQ;
    int*   degC     = (int*)(ws + OFF_DEGC);
    int*   rsC      = (int*)(ws + OFF_RSC);
    int*   row_start= (int*)(ws + OFF_ROWSTART);
    int*   csr_src  = (int*)(ws + OFF_CSR);
    int*   bsum     = (int*)(ws + OFF_BSUM);
    int*   rank     = (int*)(ws + OFF_RANK);
    float* partials = ws + OFF_X1F;

    // ---- prep (feat->bf16, W->Wt bf16, zero stats) ----
    k_prep<<<3479, 256, 0, stream>>>(feature, lin_w, Xb, Wt, hs_small);

    // ---- fused: hs_partial | eigen-MLP | LDS-rank (zero device atomics) ----
    k_stage2<<<HSP_BLOCKS + 32 + RANKB, 256, 0, stream>>>(evecs, feature, partials,
                                                          evals, ew0, eb0, ew1, eb1, ew2, eb2,
                                                          ef, degC, edge_dst, rank);

    // ---- fused: scan1 | hs_reduce ----
    k_stage3<<<SCAN_BLK + 128, 1024, 0, stream>>>(degC, row_start, bsum, partials, hs_small);
    k_scan3<<<SCAN_BLK, 1024, 0, stream>>>(degC, row_start, bsum, dsq, rsC);

    // ---- fused: csr scatter | hs_apply ----
    k_stage6<<<3125 + 1563, 256, 0, stream>>>(edge_src, edge_dst, rank, rsC, csr_src,
                                              Xb, evecs, hs_small, ef);

    // ---- Chebyshev recurrence (all-bf16 state in Xb column slots) ----
    const int GBLK = (N_NODES * 64 + 255) / 256;
    k_gather<<<GBLK, 256, 0, stream>>>(row_start, csr_src, dsq,
                                       Xb + 0, Xb + 0, (const unsigned short*)nullptr,
                                       Xb + IN_F, lambda_max, 1);
    k_gather<<<GBLK, 256, 0, stream>>>(row_start, csr_src, dsq,
                                       Xb + IN_F, Xb + IN_F, Xb + 0,
                                       Xb + 2 * IN_F, lambda_max, 0);
    k_gather<<<GBLK, 256, 0, stream>>>(row_start, csr_src, dsq,
                                       Xb + 2 * IN_F, Xb + 2 * IN_F, Xb + IN_F,
                                       Xb + 3 * IN_F, lambda_max, 0);

    // ---- MFMA linear (+BN stats) + BN apply ----
    k_gemm<<<(N_NODES + 127) / 128, 256, 0, stream>>>(Xb, Wt, lin_b, out, colsum, colsq);
    k_bn_apply<<<(N_NODES * 32) / 256, 256, 0, stream>>>(out, colsum, colsq, bn_gamma, bn_beta);
}

// Round 6
// 373.039 us; speedup vs baseline: 1.0068x; 1.0068x over previous
//
#include <hip/hip_runtime.h>

#define N_NODES 50000
#define N_EDGES 800000
#define IN_F    128
#define OUT_F   128
#define NEIG    64
#define HDIM    128
#define BN_EPSF 1e-5f
#define XB_ROWS 50048            // 50000 padded to 128
#define XB_COLS 640
#define SCAN_BLK 49              // ceil(50000/1024)
#define HSP_BLOCKS 521           // 521*96 >= 50000
#define HSP_NODES 96
#define RED_CHUNK 33             // ceil(521/16)
#define N_CHK 16                 // edge chunks (replica dim for rank merge)
#define N_RNG 4                  // node ranges (12500 nodes -> 25KB LDS counters)
#define RANKB (N_RNG * N_CHK)    // 64 rank blocks

typedef __attribute__((ext_vector_type(8))) short short8;
typedef __attribute__((ext_vector_type(4))) float floatx4;

// ---- workspace layout (in 4-byte units) ----
#define OFF_XB      0                                   // ushort[50048*640]
#define OFF_X1F     (XB_ROWS * XB_COLS / 2)             // hs partials region
#define OFF_X2F     (OFF_X1F + N_NODES * IN_F)          // degC/rsC live here (25.6MB free)
#define OFF_DEGC    OFF_X2F                             // int[16*N] per-chunk counts
#define OFF_RSC     (OFF_X2F + N_CHK * N_NODES)         // int[16*N] chunk scatter bases
#define OFF_WT      (OFF_X2F + N_NODES * IN_F)          // ushort[640*128]
#define OFF_DSQRT   (OFF_WT + 40960)
#define OFF_HS      (OFF_DSQRT + N_NODES)
#define OFF_EF      (OFF_HS + NEIG * OUT_F)
#define OFF_COLSUM  (OFF_EF + NEIG)
#define OFF_COLSQ   (OFF_COLSUM + OUT_F)
#define OFF_DEG     (OFF_COLSQ + OUT_F)                 // (legacy, unused)
#define OFF_ROWSTART (OFF_DEG + 8 * N_NODES)
#define OFF_CSR     (OFF_ROWSTART + N_NODES + 1)
#define OFF_BSUM    (OFF_CSR + N_EDGES)                 // 64 ints
#define OFF_RANK    (OFF_BSUM + 64)                     // E ints
// end ~= 29.4M * 4B ~= 118 MB (< 128.3 MB proven in R0)

static __device__ inline unsigned short f2bf(float f) {
    union { float f; unsigned int u; } v; v.f = f;
    unsigned int r = (v.u + 0x7FFFu + ((v.u >> 16) & 1u)) >> 16;
    return (unsigned short)r;
}
static __device__ inline float bf2f(unsigned int u16) {
    union { unsigned int u; float f; } v; v.u = u16 << 16;
    return v.f;
}

// merged: feat2bf (blocks 0..3124) | wt (3125..3444) | zero stats (3445..3478)
__global__ __launch_bounds__(256) void k_prep(const float* __restrict__ feat,
                                              const float* __restrict__ W,
                                              unsigned short* __restrict__ Xb,
                                              unsigned short* __restrict__ Wt,
                                              float* __restrict__ small) {
    int b = blockIdx.x;
    if (b < 3125) {
        int t = b * 256 + threadIdx.x;           // [0, 800000)
        int n = t >> 4, c8 = (t & 15) * 8;
        float4 a = *(const float4*)&feat[n * IN_F + c8];
        float4 bb = *(const float4*)&feat[n * IN_F + c8 + 4];
        ushort4 o0, o1;
        o0.x = f2bf(a.x); o0.y = f2bf(a.y); o0.z = f2bf(a.z); o0.w = f2bf(a.w);
        o1.x = f2bf(bb.x); o1.y = f2bf(bb.y); o1.z = f2bf(bb.z); o1.w = f2bf(bb.w);
        *(ushort4*)&Xb[(size_t)n * XB_COLS + c8]     = o0;
        *(ushort4*)&Xb[(size_t)n * XB_COLS + c8 + 4] = o1;
    } else if (b < 3445) {
        int t = (b - 3125) * 256 + threadIdx.x;  // [0, 81920)
        int k = t >> 7, n = t & 127;
        Wt[n * 640 + k] = f2bf(W[k * 128 + n]);
    } else {
        int i = (b - 3445) * 256 + threadIdx.x;
        if (i < NEIG * OUT_F + NEIG + 2 * OUT_F) small[i] = 0.0f;
    }
}

// Branch-local shared regions OVERLAID in one union: hipcc SUMS separate
// __shared__ decls across divergent branches (R5: 51.7KB -> occupancy 5.9%,
// hs_partial 2.3x slower). Union -> 25KB = max, occupancy restored.
struct HsSm  { float sEv[32 * NEIG]; float sFt[32 * IN_F]; };   // 24576 B
struct MlpSm { float z0[2][HDIM]; float red[2][HDIM]; };        // 2048 B
union StageSm {
    HsSm hs;
    MlpSm mlp;
    unsigned int cnt[6250];                                     // 25000 B
};

// fused: hs_partial (0..520) | eigen-MLP x2 (521..552) | LDS-rank (553..616)
// rank: ZERO device atomics (R0-R4: 800K memory-side RMWs = fixed ~40us toll,
// WRITE_SIZE write-through confirmed gone in R5: 44.8->22.9MB).
__global__ __launch_bounds__(256) void k_stage2(const float* __restrict__ evecs,
                                                const float* __restrict__ feat,
                                                float* __restrict__ partials,
                                                const float* __restrict__ evals,
                                                const float* __restrict__ ew0,
                                                const float* __restrict__ eb0,
                                                const float* __restrict__ ew1,
                                                const float* __restrict__ eb1,
                                                const float* __restrict__ ew2,
                                                const float* __restrict__ eb2,
                                                float* __restrict__ ef,
                                                int* __restrict__ degC,
                                                const int* __restrict__ dst,
                                                int* __restrict__ rank) {
    __shared__ __align__(16) StageSm sm;
    int b = blockIdx.x;
    int t = threadIdx.x;
    if (b < HSP_BLOCKS) {
        // ---- hs partial: block handles 96 nodes; partial C[64][128] -> partials[b]
        float* sEv = sm.hs.sEv;
        float* sFt = sm.hs.sFt;
        int e0 = (t >> 5) * 8;
        int f0 = (t & 31) * 4;
        float acc[8][4];
#pragma unroll
        for (int r = 0; r < 8; ++r)
#pragma unroll
            for (int c = 0; c < 4; ++c) acc[r][c] = 0.0f;

        int n0 = b * HSP_NODES;
        for (int ch = 0; ch < HSP_NODES; ch += 32) {
            int base = n0 + ch;
            {
                int r = t >> 3, c = (t & 7) * 8;
                int n = base + r;
                float4 a, bb;
                if (n < N_NODES) {
                    a = *(const float4*)&evecs[(size_t)n * NEIG + c];
                    bb = *(const float4*)&evecs[(size_t)n * NEIG + c + 4];
                } else {
                    a = make_float4(0, 0, 0, 0); bb = a;
                }
                *(float4*)&sEv[r * NEIG + c] = a;
                *(float4*)&sEv[r * NEIG + c + 4] = bb;
            }
            {
                int r = t >> 3, c = (t & 7) * 16;
                int n = base + r;
#pragma unroll
                for (int q = 0; q < 4; ++q) {
                    float4 v = (n < N_NODES) ? *(const float4*)&feat[(size_t)n * IN_F + c + q * 4]
                                             : make_float4(0, 0, 0, 0);
                    *(float4*)&sFt[r * IN_F + c + q * 4] = v;
                }
            }
            __syncthreads();
#pragma unroll 2
            for (int i = 0; i < 32; ++i) {
                float4 ev0 = *(float4*)&sEv[i * NEIG + e0];
                float4 ev1 = *(float4*)&sEv[i * NEIG + e0 + 4];
                float4 fv  = *(float4*)&sFt[i * IN_F + f0];
                float evv[8] = {ev0.x, ev0.y, ev0.z, ev0.w, ev1.x, ev1.y, ev1.z, ev1.w};
#pragma unroll
                for (int r = 0; r < 8; ++r) {
                    acc[r][0] += evv[r] * fv.x;
                    acc[r][1] += evv[r] * fv.y;
                    acc[r][2] += evv[r] * fv.z;
                    acc[r][3] += evv[r] * fv.w;
                }
            }
            __syncthreads();
        }
        float* p = &partials[(size_t)b * (NEIG * IN_F)];
#pragma unroll
        for (int r = 0; r < 8; ++r)
            *(float4*)&p[(e0 + r) * IN_F + f0] = make_float4(acc[r][0], acc[r][1], acc[r][2], acc[r][3]);
    } else if (b < HSP_BLOCKS + 32) {
        // ---- eigen-MLP: 2 eigenvalues per 256-thread block
        int sub = t >> 7, j = t & 127;
        int i = (b - HSP_BLOCKS) * 2 + sub;
        float ev = evals[i];
        sm.mlp.z0[sub][j] = fmaxf(0.0f, ev * ew0[j] + eb0[j]);
        __syncthreads();
        float s0 = 0.f, s1 = 0.f, s2 = 0.f, s3 = 0.f;
        for (int h = 0; h < HDIM; h += 4) {
            s0 += sm.mlp.z0[sub][h]     * ew1[(h) * HDIM + j];
            s1 += sm.mlp.z0[sub][h + 1] * ew1[(h + 1) * HDIM + j];
            s2 += sm.mlp.z0[sub][h + 2] * ew1[(h + 2) * HDIM + j];
            s3 += sm.mlp.z0[sub][h + 3] * ew1[(h + 3) * HDIM + j];
        }
        float z1 = fmaxf(0.0f, eb1[j] + s0 + s1 + s2 + s3);
        sm.mlp.red[sub][j] = z1 * ew2[j];
        __syncthreads();
        for (int off = 64; off > 0; off >>= 1) {
            if (j < off) sm.mlp.red[sub][j] += sm.mlp.red[sub][j + off];
            __syncthreads();
        }
        if (j == 0) ef[i] = sm.mlp.red[sub][0] + eb2[0];
    } else {
        // ---- LDS rank: block (g,c); g = node range [g*12500, +12500), c = edge chunk
        unsigned int* cnt = sm.cnt;             // 12500 u16 counters packed, 25 KB
        int rb = b - (HSP_BLOCKS + 32);
        int g = rb >> 4, c = rb & (N_CHK - 1);
        for (int k = t; k < 6250; k += 256) cnt[k] = 0;
        __syncthreads();
        int nlo = g * 12500;
        int ebase = c * 50000;
        for (int off = t; off < 50000; off += 256) {
            int e = ebase + off;
            int d = dst[e];
            int l = d - nlo;
            if ((unsigned)l < 12500u) {
                unsigned sh = (l & 1) * 16;
                unsigned old = atomicAdd(&cnt[l >> 1], 1u << sh);
                int lrank = (old >> sh) & 0xFFFF;
                rank[e] = lrank | (c << 24);
            }
        }
        __syncthreads();
        // per-chunk counts for this range (each (c,node) written exactly once)
        for (int k = t; k < 6250; k += 256) {
            unsigned v = cnt[k];
            int n0 = nlo + k * 2;
            degC[(size_t)c * N_NODES + n0]     = (int)(v & 0xFFFF);
            degC[(size_t)c * N_NODES + n0 + 1] = (int)(v >> 16);
        }
    }
}

// fused: scan1 (blocks 0..48) | hs_reduce (49..176), 1024 threads
__global__ __launch_bounds__(1024) void k_stage3(int* __restrict__ degC,
                                                 int* __restrict__ row_start,
                                                 int* __restrict__ bsum,
                                                 const float* __restrict__ partials,
                                                 float* __restrict__ hs_small) {
    int b = blockIdx.x;
    int t = threadIdx.x;
    if (b < SCAN_BLK) {
        __shared__ int sd[1024];
        int i = b * 1024 + t;
        int d[N_CHK];
#pragma unroll
        for (int cc = 0; cc < N_CHK; ++cc)
            d[cc] = (i < N_NODES) ? degC[(size_t)cc * N_NODES + i] : 0;
        int total = 0;
#pragma unroll
        for (int cc = 0; cc < N_CHK; ++cc) total += d[cc];
        sd[t] = total;
        __syncthreads();
        for (int off = 1; off < 1024; off <<= 1) {
            int v = (t >= off) ? sd[t - off] : 0;
            __syncthreads();
            sd[t] += v;
            __syncthreads();
        }
        if (i < N_NODES) {
            row_start[i] = sd[t] - total;
            // repurpose degC: slot0 = total degree, slot c = prefix offset of chunk c
            degC[i] = total;
            int p = d[0];
#pragma unroll
            for (int cc = 1; cc < N_CHK; ++cc) {
                degC[(size_t)cc * N_NODES + i] = p;
                p += d[cc];
            }
        }
        if (t == 1023) bsum[b] = sd[1023];
    } else {
        // split reduce: 8 elem-groups x 16 j-chunks; atomicAdd into pre-zeroed hs_small
        int b2 = b - SCAN_BLK;
        int grp = b2 & 7;
        int chunk = b2 >> 3;
        int idx = grp * 1024 + t;
        int j0 = chunk * RED_CHUNK;
        int j1 = min(j0 + RED_CHUNK, HSP_BLOCKS);
        float s = 0.0f;
        for (int j = j0; j < j1; ++j) s += partials[(size_t)j * (NEIG * IN_F) + idx];
        atomicAdd(&hs_small[idx], s);
    }
}

// scan3 with inlined scan2: each block redundantly wave-prefixes the 49 bsum totals
__global__ __launch_bounds__(1024) void k_scan3(const int* __restrict__ degC,
                                                int* __restrict__ row_start,
                                                const int* __restrict__ bsum,
                                                float* __restrict__ dsq,
                                                int* __restrict__ rsC) {
    __shared__ int sOff;
    int t = threadIdx.x;
    if (t < 64) {
        int orig = (t < SCAN_BLK) ? bsum[t] : 0;
        int v = orig;
        for (int off = 1; off < 64; off <<= 1) {
            int u = __shfl_up(v, off);
            if (t >= off) v += u;
        }
        if (t == blockIdx.x) sOff = v - orig;   // exclusive prefix for this block
    }
    __syncthreads();
    int i = blockIdx.x * 1024 + t;
    if (i < N_NODES) {
        int r = row_start[i] + sOff;
        row_start[i] = r;
        rsC[i] = r;
#pragma unroll
        for (int cc = 1; cc < N_CHK; ++cc)
            rsC[(size_t)cc * N_NODES + i] = r + degC[(size_t)cc * N_NODES + i];
        dsq[i] = rsqrtf((float)max(degC[i], 1));
    }
    if (i == 0) row_start[N_NODES] = N_EDGES;
}

// fused: csr scatter (blocks 0..3124) | hs_apply (3125..4687)
__global__ __launch_bounds__(256) void k_stage6(const int* __restrict__ src,
                                                const int* __restrict__ dst,
                                                const int* __restrict__ rank,
                                                const int* __restrict__ rsC,
                                                int* __restrict__ csr_src,
                                                unsigned short* __restrict__ Xb,
                                                const float* __restrict__ evecs,
                                                const float* __restrict__ hs_small,
                                                const float* __restrict__ ef) {
    int b = blockIdx.x;
    int t = threadIdx.x;
    if (b < 3125) {
        int e = b * 256 + t;
        if (e < N_EDGES) {
            int rv = rank[e];
            int c = rv >> 24;
            csr_src[rsC[(size_t)c * N_NODES + dst[e]] + (rv & 0xFFFFFF)] = src[e];
        }
    } else {
        __shared__ float sShs[NEIG * HDIM];
        __shared__ float sEv[32 * NEIG];
        int n0 = (b - 3125) * 32;
        {
            float efv = ef[t >> 2];
            int pbase = t * 32;
#pragma unroll
            for (int q = 0; q < 8; ++q) {
                float4 v = *(const float4*)&hs_small[pbase + q * 4];
                v.x *= efv; v.y *= efv; v.z *= efv; v.w *= efv;
                *(float4*)&sShs[pbase + q * 4] = v;
            }
        }
        {
            int r = t >> 3, c = (t & 7) * 8;
            int n = n0 + r;
            float4 a, bb;
            if (n < N_NODES) {
                a = *(const float4*)&evecs[(size_t)n * NEIG + c];
                bb = *(const float4*)&evecs[(size_t)n * NEIG + c + 4];
            } else {
                a = make_float4(0, 0, 0, 0); bb = a;
            }
            *(float4*)&sEv[r * NEIG + c] = a;
            *(float4*)&sEv[r * NEIG + c + 4] = bb;
        }
        __syncthreads();
        int nb = (t >> 5) * 4;
        int f0 = (t & 31) * 4;
        float acc[4][4];
#pragma unroll
        for (int q = 0; q < 4; ++q)
#pragma unroll
            for (int c = 0; c < 4; ++c) acc[q][c] = 0.0f;
        for (int e = 0; e < NEIG; ++e) {
            float4 sv = *(float4*)&sShs[e * HDIM + f0];
#pragma unroll
            for (int q = 0; q < 4; ++q) {
                float evv = sEv[(nb + q) * NEIG + e];
                acc[q][0] += evv * sv.x;
                acc[q][1] += evv * sv.y;
                acc[q][2] += evv * sv.z;
                acc[q][3] += evv * sv.w;
            }
        }
#pragma unroll
        for (int q = 0; q < 4; ++q) {
            int n = n0 + nb + q;
            if (n < N_NODES) {
                ushort4 o;
                o.x = f2bf(acc[q][0]); o.y = f2bf(acc[q][1]);
                o.z = f2bf(acc[q][2]); o.w = f2bf(acc[q][3]);
                *(ushort4*)&Xb[(size_t)n * XB_COLS + 4 * IN_F + f0] = o;
            }
        }
    }
}

// One wave per node, all-bf16 state. 16x/8x/4x unrolled edge loop: up to 16
// independent 256 B row-loads in flight per wave. R2 LESSON: do NOT restructure
// into wider per-lane loads + lane-split — it demotes the unrolled arrays to
// scratch (VGPR 20, WRITE_SIZE 206MB) and runs 7x slower. This form is proven
// register-resident at ~40us/launch.
__global__ __launch_bounds__(256) void k_gather(const int* __restrict__ row_start,
                                                const int* __restrict__ csr_src,
                                                const float* __restrict__ dsq,
                                                const unsigned short* __restrict__ srcb,
                                                const unsigned short* __restrict__ prevb,
                                                const unsigned short* __restrict__ ppb,
                                                unsigned short* __restrict__ outb,
                                                const float* __restrict__ lm, int first) {
    int n = (blockIdx.x * 256 + threadIdx.x) >> 6;
    int lane = threadIdx.x & 63;
    if (n >= N_NODES) return;
    float rn = 2.0f / lm[0];
    float ax = 0.0f, ay = 0.0f;
    int beg = row_start[n], end = row_start[n + 1];
    int i = beg;
    for (; i + 16 <= end; i += 16) {
        int s[16]; float c[16]; unsigned int p[16];
#pragma unroll
        for (int j = 0; j < 16; ++j) s[j] = __builtin_amdgcn_readfirstlane(csr_src[i + j]);
#pragma unroll
        for (int j = 0; j < 16; ++j) c[j] = dsq[s[j]];
#pragma unroll
        for (int j = 0; j < 16; ++j)
            p[j] = *(const unsigned int*)&srcb[(size_t)s[j] * XB_COLS + lane * 2];
#pragma unroll
        for (int j = 0; j < 16; ++j) {
            ax += c[j] * bf2f(p[j] & 0xffffu);
            ay += c[j] * bf2f(p[j] >> 16);
        }
    }
    for (; i + 8 <= end; i += 8) {
        int s[8]; float c[8]; unsigned int p[8];
#pragma unroll
        for (int j = 0; j < 8; ++j) s[j] = __builtin_amdgcn_readfirstlane(csr_src[i + j]);
#pragma unroll
        for (int j = 0; j < 8; ++j) c[j] = dsq[s[j]];
#pragma unroll
        for (int j = 0; j < 8; ++j)
            p[j] = *(const unsigned int*)&srcb[(size_t)s[j] * XB_COLS + lane * 2];
#pragma unroll
        for (int j = 0; j < 8; ++j) {
            ax += c[j] * bf2f(p[j] & 0xffffu);
            ay += c[j] * bf2f(p[j] >> 16);
        }
    }
    for (; i + 4 <= end; i += 4) {
        int s[4]; float c[4]; unsigned int p[4];
#pragma unroll
        for (int j = 0; j < 4; ++j) s[j] = __builtin_amdgcn_readfirstlane(csr_src[i + j]);
#pragma unroll
        for (int j = 0; j < 4; ++j) c[j] = dsq[s[j]];
#pragma unroll
        for (int j = 0; j < 4; ++j)
            p[j] = *(const unsigned int*)&srcb[(size_t)s[j] * XB_COLS + lane * 2];
#pragma unroll
        for (int j = 0; j < 4; ++j) {
            ax += c[j] * bf2f(p[j] & 0xffffu);
            ay += c[j] * bf2f(p[j] >> 16);
        }
    }
    for (; i < end; ++i) {
        int s = __builtin_amdgcn_readfirstlane(csr_src[i]);
        float sc = dsq[s];
        unsigned int pv = *(const unsigned int*)&srcb[(size_t)s * XB_COLS + lane * 2];
        ax += sc * bf2f(pv & 0xffffu);
        ay += sc * bf2f(pv >> 16);
    }
    float ds = dsq[n];
    float a = (first ? -rn : -2.0f * rn) * ds;
    float b = first ? (rn - 1.0f) : 2.0f * (rn - 1.0f);
    unsigned int pu = *(const unsigned int*)&prevb[(size_t)n * XB_COLS + lane * 2];
    float rx = a * ax + b * bf2f(pu & 0xffffu);
    float ry = a * ay + b * bf2f(pu >> 16);
    if (ppb) {
        unsigned int qu = *(const unsigned int*)&ppb[(size_t)n * XB_COLS + lane * 2];
        rx -= bf2f(qu & 0xffffu);
        ry -= bf2f(qu >> 16);
    }
    unsigned int packed = (unsigned int)f2bf(rx) | ((unsigned int)f2bf(ry) << 16);
    *(unsigned int*)&outb[(size_t)n * XB_COLS + lane * 2] = packed;
}

// MFMA bf16 GEMM with fused BN column-stats (shfl + per-wave LDS, no LDS atomics)
__global__ __launch_bounds__(256) void k_gemm(const unsigned short* __restrict__ Xb,
                                              const unsigned short* __restrict__ Wt,
                                              const float* __restrict__ bias,
                                              float* __restrict__ out,
                                              float* __restrict__ colsum,
                                              float* __restrict__ colsq) {
    __shared__ unsigned short sA[128 * 32];
    __shared__ unsigned short sB[128 * 32];
    __shared__ float cs[4][OUT_F];
    __shared__ float cq[4][OUT_F];
    int tid = threadIdx.x;
    int wave = tid >> 6, lane = tid & 63;
    int quad = lane >> 4, m16 = lane & 15;
    int row0 = blockIdx.x * 128;

    floatx4 acc[2][8];
#pragma unroll
    for (int mt = 0; mt < 2; ++mt)
#pragma unroll
        for (int nt = 0; nt < 8; ++nt) acc[mt][nt] = (floatx4)(0.0f);

    int r  = tid >> 2;
    int c8 = (tid & 3) * 8;
    int gr0 = min(row0 + r, N_NODES - 1);
    int gr1 = min(row0 + r + 64, N_NODES - 1);

    for (int k0 = 0; k0 < 640; k0 += 32) {
        *(uint4*)&sA[r * 32 + c8]        = *(const uint4*)&Xb[(size_t)gr0 * XB_COLS + k0 + c8];
        *(uint4*)&sA[(r + 64) * 32 + c8] = *(const uint4*)&Xb[(size_t)gr1 * XB_COLS + k0 + c8];
        *(uint4*)&sB[r * 32 + c8]        = *(const uint4*)&Wt[r * 640 + k0 + c8];
        *(uint4*)&sB[(r + 64) * 32 + c8] = *(const uint4*)&Wt[(r + 64) * 640 + k0 + c8];
        __syncthreads();
        short8 a0 = *(short8*)&sA[(wave * 32 + m16) * 32 + quad * 8];
        short8 a1 = *(short8*)&sA[(wave * 32 + 16 + m16) * 32 + quad * 8];
#pragma unroll
        for (int nt = 0; nt < 8; ++nt) {
            short8 b = *(short8*)&sB[(nt * 16 + m16) * 32 + quad * 8];
            acc[0][nt] = __builtin_amdgcn_mfma_f32_16x16x32_bf16(a0, b, acc[0][nt], 0, 0, 0);
            acc[1][nt] = __builtin_amdgcn_mfma_f32_16x16x32_bf16(a1, b, acc[1][nt], 0, 0, 0);
        }
        __syncthreads();
    }
#pragma unroll
    for (int nt = 0; nt < 8; ++nt) {
        int col = nt * 16 + m16;
        float bb = bias[col];
        float sv = 0.0f, sq = 0.0f;
#pragma unroll
        for (int mt = 0; mt < 2; ++mt) {
            int rbase = row0 + wave * 32 + mt * 16 + quad * 4;
#pragma unroll
            for (int reg = 0; reg < 4; ++reg) {
                int row = rbase + reg;
                if (row < N_NODES) {
                    float w = acc[mt][nt][reg] + bb;
                    out[(size_t)row * OUT_F + col] = w;
                    sv += w;
                    sq += w * w;
                }
            }
        }
        sv += __shfl_down(sv, 32); sq += __shfl_down(sq, 32);
        sv += __shfl_down(sv, 16); sq += __shfl_down(sq, 16);
        if (lane < 16) { cs[wave][col] = sv; cq[wave][col] = sq; }
    }
    __syncthreads();
    if (tid < OUT_F) {
        float s = cs[0][tid] + cs[1][tid] + cs[2][tid] + cs[3][tid];
        float q = cq[0][tid] + cq[1][tid] + cq[2][tid] + cq[3][tid];
        atomicAdd(&colsum[tid], s);
        atomicAdd(&colsq[tid], q);
    }
}

__global__ void k_bn_apply(float* __restrict__ out, const float* __restrict__ colsum,
                           const float* __restrict__ colsq, const float* __restrict__ gamma,
                           const float* __restrict__ beta) {
    int t = blockIdx.x * 256 + threadIdx.x;
    int n = t >> 5, c = t & 31;
    float4 v = *(float4*)&out[n * OUT_F + c * 4];
    float4 s = *(const float4*)&colsum[c * 4];
    float4 q = *(const float4*)&colsq[c * 4];
    float4 g = *(const float4*)&gamma[c * 4];
    float4 b = *(const float4*)&beta[c * 4];
    const float invN = 1.0f / (float)N_NODES;
    float mux = s.x * invN, muy = s.y * invN, muz = s.z * invN, muw = s.w * invN;
    float ix = rsqrtf(q.x * invN - mux * mux + BN_EPSF);
    float iy = rsqrtf(q.y * invN - muy * muy + BN_EPSF);
    float iz = rsqrtf(q.z * invN - muz * muz + BN_EPSF);
    float iw = rsqrtf(q.w * invN - muw * muw + BN_EPSF);
    v.x = fmaxf(0.0f, (v.x - mux) * ix * g.x + b.x);
    v.y = fmaxf(0.0f, (v.y - muy) * iy * g.y + b.y);
    v.z = fmaxf(0.0f, (v.z - muz) * iz * g.z + b.z);
    v.w = fmaxf(0.0f, (v.w - muw) * iw * g.w + b.w);
    *(float4*)&out[n * OUT_F + c * 4] = v;
}

extern "C" void kernel_launch(void* const* d_in, const int* in_sizes, int n_in,
                              void* d_out, int out_size, void* d_ws, size_t ws_size,
                              hipStream_t stream) {
    const float* feature    = (const float*)d_in[0];
    const float* lin_w      = (const float*)d_in[1];
    const float* lin_b      = (const float*)d_in[2];
    const float* ew0        = (const float*)d_in[3];
    const float* eb0        = (const float*)d_in[4];
    const float* ew1        = (const float*)d_in[5];
    const float* eb1        = (const float*)d_in[6];
    const float* ew2        = (const float*)d_in[7];
    const float* eb2        = (const float*)d_in[8];
    const float* bn_gamma   = (const float*)d_in[9];
    const float* bn_beta    = (const float*)d_in[10];
    const float* lambda_max = (const float*)d_in[11];
    const float* evecs      = (const float*)d_in[12];
    const float* evals      = (const float*)d_in[13];
    const int*   edge_src   = (const int*)d_in[14];
    const int*   edge_dst   = (const int*)d_in[15];

    float* out = (float*)d_out;
    float* ws  = (float*)d_ws;
    unsigned short* Xb = (unsigned short*)(ws + OFF_XB);
    unsigned short* Wt = (unsigned short*)(ws + OFF_WT);
    float* dsq      = ws + OFF_DSQRT;
    float* hs_small = ws + OFF_HS;
    float* ef       = ws + OFF_EF;
    float* colsum   = ws + OFF_COLSUM;
    float* colsq    = ws + OFF_COLSQ;
    int*   degC     = (int*)(ws + OFF_DEGC);
    int*   rsC      = (int*)(ws + OFF_RSC);
    int*   row_start= (int*)(ws + OFF_ROWSTART);
    int*   csr_src  = (int*)(ws + OFF_CSR);
    int*   bsum     = (int*)(ws + OFF_BSUM);
    int*   rank     = (int*)(ws + OFF_RANK);
    float* partials = ws + OFF_X1F;

    // ---- prep (feat->bf16, W->Wt bf16, zero stats) ----
    k_prep<<<3479, 256, 0, stream>>>(feature, lin_w, Xb, Wt, hs_small);

    // ---- fused: hs_partial | eigen-MLP | LDS-rank (zero device atomics) ----
    k_stage2<<<HSP_BLOCKS + 32 + RANKB, 256, 0, stream>>>(evecs, feature, partials,
                                                          evals, ew0, eb0, ew1, eb1, ew2, eb2,
                                                          ef, degC, edge_dst, rank);

    // ---- fused: scan1 | hs_reduce ----
    k_stage3<<<SCAN_BLK + 128, 1024, 0, stream>>>(degC, row_start, bsum, partials, hs_small);
    k_scan3<<<SCAN_BLK, 1024, 0, stream>>>(degC, row_start, bsum, dsq, rsC);

    // ---- fused: csr scatter | hs_apply ----
    k_stage6<<<3125 + 1563, 256, 0, stream>>>(edge_src, edge_dst, rank, rsC, csr_src,
                                              Xb, evecs, hs_small, ef);

    // ---- Chebyshev recurrence (all-bf16 state in Xb column slots) ----
    const int GBLK = (N_NODES * 64 + 255) / 256;
    k_gather<<<GBLK, 256, 0, stream>>>(row_start, csr_src, dsq,
                                       Xb + 0, Xb + 0, (const unsigned short*)nullptr,
                                       Xb + IN_F, lambda_max, 1);
    k_gather<<<GBLK, 256, 0, stream>>>(row_start, csr_src, dsq,
                                       Xb + IN_F, Xb + IN_F, Xb + 0,
                                       Xb + 2 * IN_F, lambda_max, 0);
    k_gather<<<GBLK, 256, 0, stream>>>(row_start, csr_src, dsq,
                                       Xb + 2 * IN_F, Xb + 2 * IN_F, Xb + IN_F,
                                       Xb + 3 * IN_F, lambda_max, 0);

    // ---- MFMA linear (+BN stats) + BN apply ----
    k_gemm<<<(N_NODES + 127) / 128, 256, 0, stream>>>(Xb, Wt, lin_b, out, colsum, colsq);
    k_bn_apply<<<(N_NODES * 32) / 256, 256, 0, stream>>>(out, colsum, colsq, bn_gamma, bn_beta);
}

// Round 7
// 329.368 us; speedup vs baseline: 1.1402x; 1.1326x over previous
//
#include <hip/hip_runtime.h>

#define N_NODES 50000
#define N_EDGES 800000
#define IN_F    128
#define OUT_F   128
#define NEIG    64
#define HDIM    128
#define BN_EPSF 1e-5f
#define XB_ROWS 50048            // 50000 padded to 128
#define XB_COLS 640
#define SCAN_BLK 49              // ceil(50000/1024)
#define HSP_BLOCKS 521           // 521*96 >= 50000
#define HSP_NODES 96
#define RED_CHUNK 33             // ceil(521/16)
#define N_CHK 32                 // edge chunks (replica dim for rank merge)
#define N_RNG 4                  // node ranges (12500 nodes -> 25KB LDS counters)
#define RANKB (N_RNG * N_CHK)    // 128 rank blocks
#define CHUNK_E (N_EDGES / N_CHK) // 25000 edges per chunk

typedef __attribute__((ext_vector_type(8))) short short8;
typedef __attribute__((ext_vector_type(4))) float floatx4;

// ---- workspace layout (in 4-byte units) ----
#define OFF_XB      0                                   // ushort[50048*640]
#define OFF_X1F     (XB_ROWS * XB_COLS / 2)             // hs partials region
#define OFF_X2F     (OFF_X1F + N_NODES * IN_F)          // degC/rsC live here (25.6MB free)
#define OFF_DEGC    OFF_X2F                             // int[32*N] per-chunk counts
#define OFF_RSC     (OFF_X2F + N_CHK * N_NODES)         // int[32*N] chunk scatter bases
#define OFF_WT      (OFF_X2F + N_NODES * IN_F)          // ushort[640*128]
#define OFF_DSQRT   (OFF_WT + 40960)
#define OFF_HS      (OFF_DSQRT + N_NODES)
#define OFF_EF      (OFF_HS + NEIG * OUT_F)
#define OFF_COLSUM  (OFF_EF + NEIG)
#define OFF_COLSQ   (OFF_COLSUM + OUT_F)
#define OFF_DEG     (OFF_COLSQ + OUT_F)                 // (legacy, unused)
#define OFF_ROWSTART (OFF_DEG + 8 * N_NODES)
#define OFF_CSR     (OFF_ROWSTART + N_NODES + 1)
#define OFF_BSUM    (OFF_CSR + N_EDGES)                 // 64 ints
#define OFF_RANK    (OFF_BSUM + 64)                     // E ints
// end ~= 29.4M * 4B ~= 118 MB (< 128.3 MB proven in R0)

static __device__ inline unsigned short f2bf(float f) {
    union { float f; unsigned int u; } v; v.f = f;
    unsigned int r = (v.u + 0x7FFFu + ((v.u >> 16) & 1u)) >> 16;
    return (unsigned short)r;
}
static __device__ inline float bf2f(unsigned int u16) {
    union { unsigned int u; float f; } v; v.u = u16 << 16;
    return v.f;
}

// merged: feat2bf (blocks 0..3124) | wt (3125..3444) | zero stats (3445..3478)
__global__ __launch_bounds__(256) void k_prep(const float* __restrict__ feat,
                                              const float* __restrict__ W,
                                              unsigned short* __restrict__ Xb,
                                              unsigned short* __restrict__ Wt,
                                              float* __restrict__ small) {
    int b = blockIdx.x;
    if (b < 3125) {
        int t = b * 256 + threadIdx.x;           // [0, 800000)
        int n = t >> 4, c8 = (t & 15) * 8;
        float4 a = *(const float4*)&feat[n * IN_F + c8];
        float4 bb = *(const float4*)&feat[n * IN_F + c8 + 4];
        ushort4 o0, o1;
        o0.x = f2bf(a.x); o0.y = f2bf(a.y); o0.z = f2bf(a.z); o0.w = f2bf(a.w);
        o1.x = f2bf(bb.x); o1.y = f2bf(bb.y); o1.z = f2bf(bb.z); o1.w = f2bf(bb.w);
        *(ushort4*)&Xb[(size_t)n * XB_COLS + c8]     = o0;
        *(ushort4*)&Xb[(size_t)n * XB_COLS + c8 + 4] = o1;
    } else if (b < 3445) {
        int t = (b - 3125) * 256 + threadIdx.x;  // [0, 81920)
        int k = t >> 7, n = t & 127;
        Wt[n * 640 + k] = f2bf(W[k * 128 + n]);
    } else {
        int i = (b - 3445) * 256 + threadIdx.x;
        if (i < NEIG * OUT_F + NEIG + 2 * OUT_F) small[i] = 0.0f;
    }
}

// Branch-local shared regions OVERLAID in one union: hipcc SUMS separate
// __shared__ decls across divergent branches (R5 lesson: 51.7KB -> occupancy
// 5.9%, hs_partial 2.3x slower). Union -> 25KB = max, occupancy restored.
struct HsSm  { float sEv[32 * NEIG]; float sFt[32 * IN_F]; };   // 24576 B
struct MlpSm { float z0[2][HDIM]; float red[2][HDIM]; };        // 2048 B
union StageSm {
    HsSm hs;
    MlpSm mlp;
    unsigned int cnt[6250];                                     // 25000 B
};

// fused: hs_partial (0..520) | eigen-MLP x2 (521..552) | LDS-rank (553..680)
// rank: ZERO device atomics (R0-R4: 800K memory-side RMWs = fixed ~40us toll,
// write-through confirmed gone in R5: WRITE_SIZE 44.8->22.9MB). R6 lesson: the
// 64-block serial-loop variant was a latency-bound 60us tail (occupancy 6%) —
// now 128 blocks x 4-deep ILP batches (load 4 dsts, 4 independent LDS atomics,
// 4 stores) so per-batch latency is amortized 4x.
__global__ __launch_bounds__(256) void k_stage2(const float* __restrict__ evecs,
                                                const float* __restrict__ feat,
                                                float* __restrict__ partials,
                                                const float* __restrict__ evals,
                                                const float* __restrict__ ew0,
                                                const float* __restrict__ eb0,
                                                const float* __restrict__ ew1,
                                                const float* __restrict__ eb1,
                                                const float* __restrict__ ew2,
                                                const float* __restrict__ eb2,
                                                float* __restrict__ ef,
                                                int* __restrict__ degC,
                                                const int* __restrict__ dst,
                                                int* __restrict__ rank) {
    __shared__ __align__(16) StageSm sm;
    int b = blockIdx.x;
    int t = threadIdx.x;
    if (b < HSP_BLOCKS) {
        // ---- hs partial: block handles 96 nodes; partial C[64][128] -> partials[b]
        float* sEv = sm.hs.sEv;
        float* sFt = sm.hs.sFt;
        int e0 = (t >> 5) * 8;
        int f0 = (t & 31) * 4;
        float acc[8][4];
#pragma unroll
        for (int r = 0; r < 8; ++r)
#pragma unroll
            for (int c = 0; c < 4; ++c) acc[r][c] = 0.0f;

        int n0 = b * HSP_NODES;
        for (int ch = 0; ch < HSP_NODES; ch += 32) {
            int base = n0 + ch;
            {
                int r = t >> 3, c = (t & 7) * 8;
                int n = base + r;
                float4 a, bb;
                if (n < N_NODES) {
                    a = *(const float4*)&evecs[(size_t)n * NEIG + c];
                    bb = *(const float4*)&evecs[(size_t)n * NEIG + c + 4];
                } else {
                    a = make_float4(0, 0, 0, 0); bb = a;
                }
                *(float4*)&sEv[r * NEIG + c] = a;
                *(float4*)&sEv[r * NEIG + c + 4] = bb;
            }
            {
                int r = t >> 3, c = (t & 7) * 16;
                int n = base + r;
#pragma unroll
                for (int q = 0; q < 4; ++q) {
                    float4 v = (n < N_NODES) ? *(const float4*)&feat[(size_t)n * IN_F + c + q * 4]
                                             : make_float4(0, 0, 0, 0);
                    *(float4*)&sFt[r * IN_F + c + q * 4] = v;
                }
            }
            __syncthreads();
#pragma unroll 2
            for (int i = 0; i < 32; ++i) {
                float4 ev0 = *(float4*)&sEv[i * NEIG + e0];
                float4 ev1 = *(float4*)&sEv[i * NEIG + e0 + 4];
                float4 fv  = *(float4*)&sFt[i * IN_F + f0];
                float evv[8] = {ev0.x, ev0.y, ev0.z, ev0.w, ev1.x, ev1.y, ev1.z, ev1.w};
#pragma unroll
                for (int r = 0; r < 8; ++r) {
                    acc[r][0] += evv[r] * fv.x;
                    acc[r][1] += evv[r] * fv.y;
                    acc[r][2] += evv[r] * fv.z;
                    acc[r][3] += evv[r] * fv.w;
                }
            }
            __syncthreads();
        }
        float* p = &partials[(size_t)b * (NEIG * IN_F)];
#pragma unroll
        for (int r = 0; r < 8; ++r)
            *(float4*)&p[(e0 + r) * IN_F + f0] = make_float4(acc[r][0], acc[r][1], acc[r][2], acc[r][3]);
    } else if (b < HSP_BLOCKS + 32) {
        // ---- eigen-MLP: 2 eigenvalues per 256-thread block
        int sub = t >> 7, j = t & 127;
        int i = (b - HSP_BLOCKS) * 2 + sub;
        float ev = evals[i];
        sm.mlp.z0[sub][j] = fmaxf(0.0f, ev * ew0[j] + eb0[j]);
        __syncthreads();
        float s0 = 0.f, s1 = 0.f, s2 = 0.f, s3 = 0.f;
        for (int h = 0; h < HDIM; h += 4) {
            s0 += sm.mlp.z0[sub][h]     * ew1[(h) * HDIM + j];
            s1 += sm.mlp.z0[sub][h + 1] * ew1[(h + 1) * HDIM + j];
            s2 += sm.mlp.z0[sub][h + 2] * ew1[(h + 2) * HDIM + j];
            s3 += sm.mlp.z0[sub][h + 3] * ew1[(h + 3) * HDIM + j];
        }
        float z1 = fmaxf(0.0f, eb1[j] + s0 + s1 + s2 + s3);
        sm.mlp.red[sub][j] = z1 * ew2[j];
        __syncthreads();
        for (int off = 64; off > 0; off >>= 1) {
            if (j < off) sm.mlp.red[sub][j] += sm.mlp.red[sub][j + off];
            __syncthreads();
        }
        if (j == 0) ef[i] = sm.mlp.red[sub][0] + eb2[0];
    } else {
        // ---- LDS rank: block (g,c); g = node range [g*12500, +12500), c = edge chunk
        unsigned int* cnt = sm.cnt;             // 12500 u16 counters packed, 25 KB
        int rb = b - (HSP_BLOCKS + 32);
        int g = rb >> 5, c = rb & (N_CHK - 1);
        for (int k = t; k < 6250; k += 256) cnt[k] = 0;
        __syncthreads();
        int nlo = g * 12500;
        int ebase = c * CHUNK_E;
        for (int off0 = 0; off0 < CHUNK_E; off0 += 1024) {
            int d0[4];
#pragma unroll
            for (int k = 0; k < 4; ++k) {
                int o = off0 + k * 256 + t;
                d0[k] = (o < CHUNK_E) ? dst[ebase + o] : -1;
            }
#pragma unroll
            for (int k = 0; k < 4; ++k) {
                int o = off0 + k * 256 + t;
                int l = d0[k] - nlo;
                if ((unsigned)l < 12500u) {
                    unsigned sh = (l & 1) * 16;
                    unsigned old = atomicAdd(&cnt[l >> 1], 1u << sh);
                    rank[ebase + o] = ((old >> sh) & 0xFFFF) | (c << 24);
                }
            }
        }
        __syncthreads();
        // per-chunk counts for this range (each (c,node) written exactly once)
        for (int k = t; k < 6250; k += 256) {
            unsigned v = cnt[k];
            int n0 = nlo + k * 2;
            degC[(size_t)c * N_NODES + n0]     = (int)(v & 0xFFFF);
            degC[(size_t)c * N_NODES + n0 + 1] = (int)(v >> 16);
        }
    }
}

// fused: scan1 (blocks 0..48) | hs_reduce (49..176), 1024 threads
// scan1 merges 32 chunk-count arrays with a two-pass serial loop (2 live regs,
// no d[32] array -> no spill at 1024 threads).
__global__ __launch_bounds__(1024) void k_stage3(int* __restrict__ degC,
                                                 int* __restrict__ row_start,
                                                 int* __restrict__ bsum,
                                                 const float* __restrict__ partials,
                                                 float* __restrict__ hs_small) {
    int b = blockIdx.x;
    int t = threadIdx.x;
    if (b < SCAN_BLK) {
        __shared__ int sd[1024];
        int i = b * 1024 + t;
        int total = 0;
        if (i < N_NODES) {
#pragma unroll 8
            for (int cc = 0; cc < N_CHK; ++cc)
                total += degC[(size_t)cc * N_NODES + i];
        }
        sd[t] = total;
        __syncthreads();
        for (int off = 1; off < 1024; off <<= 1) {
            int v = (t >= off) ? sd[t - off] : 0;
            __syncthreads();
            sd[t] += v;
            __syncthreads();
        }
        if (i < N_NODES) {
            row_start[i] = sd[t] - total;
            // repurpose degC: slot0 = total degree, slot c = prefix offset of chunk c
            int p = degC[i];
            for (int cc = 1; cc < N_CHK; ++cc) {
                int v = degC[(size_t)cc * N_NODES + i];
                degC[(size_t)cc * N_NODES + i] = p;
                p += v;
            }
            degC[i] = p;    // total
        }
        if (t == 1023) bsum[b] = sd[1023];
    } else {
        // split reduce: 8 elem-groups x 16 j-chunks; atomicAdd into pre-zeroed hs_small
        int b2 = b - SCAN_BLK;
        int grp = b2 & 7;
        int chunk = b2 >> 3;
        int idx = grp * 1024 + t;
        int j0 = chunk * RED_CHUNK;
        int j1 = min(j0 + RED_CHUNK, HSP_BLOCKS);
        float s = 0.0f;
        for (int j = j0; j < j1; ++j) s += partials[(size_t)j * (NEIG * IN_F) + idx];
        atomicAdd(&hs_small[idx], s);
    }
}

// scan3 with inlined scan2: each block redundantly wave-prefixes the 49 bsum totals
__global__ __launch_bounds__(1024) void k_scan3(const int* __restrict__ degC,
                                                int* __restrict__ row_start,
                                                const int* __restrict__ bsum,
                                                float* __restrict__ dsq,
                                                int* __restrict__ rsC) {
    __shared__ int sOff;
    int t = threadIdx.x;
    if (t < 64) {
        int orig = (t < SCAN_BLK) ? bsum[t] : 0;
        int v = orig;
        for (int off = 1; off < 64; off <<= 1) {
            int u = __shfl_up(v, off);
            if (t >= off) v += u;
        }
        if (t == blockIdx.x) sOff = v - orig;   // exclusive prefix for this block
    }
    __syncthreads();
    int i = blockIdx.x * 1024 + t;
    if (i < N_NODES) {
        int r = row_start[i] + sOff;
        row_start[i] = r;
        rsC[i] = r;
        for (int cc = 1; cc < N_CHK; ++cc)
            rsC[(size_t)cc * N_NODES + i] = r + degC[(size_t)cc * N_NODES + i];
        dsq[i] = rsqrtf((float)max(degC[i], 1));
    }
    if (i == 0) row_start[N_NODES] = N_EDGES;
}

// fused: csr scatter (blocks 0..3124) | hs_apply (3125..4687)
__global__ __launch_bounds__(256) void k_stage6(const int* __restrict__ src,
                                                const int* __restrict__ dst,
                                                const int* __restrict__ rank,
                                                const int* __restrict__ rsC,
                                                int* __restrict__ csr_src,
                                                unsigned short* __restrict__ Xb,
                                                const float* __restrict__ evecs,
                                                const float* __restrict__ hs_small,
                                                const float* __restrict__ ef) {
    int b = blockIdx.x;
    int t = threadIdx.x;
    if (b < 3125) {
        int e = b * 256 + t;
        if (e < N_EDGES) {
            int rv = rank[e];
            int c = rv >> 24;
            csr_src[rsC[(size_t)c * N_NODES + dst[e]] + (rv & 0xFFFFFF)] = src[e];
        }
    } else {
        __shared__ float sShs[NEIG * HDIM];
        __shared__ float sEv[32 * NEIG];
        int n0 = (b - 3125) * 32;
        {
            float efv = ef[t >> 2];
            int pbase = t * 32;
#pragma unroll
            for (int q = 0; q < 8; ++q) {
                float4 v = *(const float4*)&hs_small[pbase + q * 4];
                v.x *= efv; v.y *= efv; v.z *= efv; v.w *= efv;
                *(float4*)&sShs[pbase + q * 4] = v;
            }
        }
        {
            int r = t >> 3, c = (t & 7) * 8;
            int n = n0 + r;
            float4 a, bb;
            if (n < N_NODES) {
                a = *(const float4*)&evecs[(size_t)n * NEIG + c];
                bb = *(const float4*)&evecs[(size_t)n * NEIG + c + 4];
            } else {
                a = make_float4(0, 0, 0, 0); bb = a;
            }
            *(float4*)&sEv[r * NEIG + c] = a;
            *(float4*)&sEv[r * NEIG + c + 4] = bb;
        }
        __syncthreads();
        int nb = (t >> 5) * 4;
        int f0 = (t & 31) * 4;
        float acc[4][4];
#pragma unroll
        for (int q = 0; q < 4; ++q)
#pragma unroll
            for (int c = 0; c < 4; ++c) acc[q][c] = 0.0f;
        for (int e = 0; e < NEIG; ++e) {
            float4 sv = *(float4*)&sShs[e * HDIM + f0];
#pragma unroll
            for (int q = 0; q < 4; ++q) {
                float evv = sEv[(nb + q) * NEIG + e];
                acc[q][0] += evv * sv.x;
                acc[q][1] += evv * sv.y;
                acc[q][2] += evv * sv.z;
                acc[q][3] += evv * sv.w;
            }
        }
#pragma unroll
        for (int q = 0; q < 4; ++q) {
            int n = n0 + nb + q;
            if (n < N_NODES) {
                ushort4 o;
                o.x = f2bf(acc[q][0]); o.y = f2bf(acc[q][1]);
                o.z = f2bf(acc[q][2]); o.w = f2bf(acc[q][3]);
                *(ushort4*)&Xb[(size_t)n * XB_COLS + 4 * IN_F + f0] = o;
            }
        }
    }
}

// One wave per node, all-bf16 state. 16x/8x/4x unrolled edge loop: up to 16
// independent 256 B row-loads in flight per wave. R2 LESSON: do NOT restructure
// into wider per-lane loads + lane-split — it demotes the unrolled arrays to
// scratch (VGPR 20, WRITE_SIZE 206MB) and runs 7x slower. This form is proven
// register-resident at ~40us/launch.
__global__ __launch_bounds__(256) void k_gather(const int* __restrict__ row_start,
                                                const int* __restrict__ csr_src,
                                                const float* __restrict__ dsq,
                                                const unsigned short* __restrict__ srcb,
                                                const unsigned short* __restrict__ prevb,
                                                const unsigned short* __restrict__ ppb,
                                                unsigned short* __restrict__ outb,
                                                const float* __restrict__ lm, int first) {
    int n = (blockIdx.x * 256 + threadIdx.x) >> 6;
    int lane = threadIdx.x & 63;
    if (n >= N_NODES) return;
    float rn = 2.0f / lm[0];
    float ax = 0.0f, ay = 0.0f;
    int beg = row_start[n], end = row_start[n + 1];
    int i = beg;
    for (; i + 16 <= end; i += 16) {
        int s[16]; float c[16]; unsigned int p[16];
#pragma unroll
        for (int j = 0; j < 16; ++j) s[j] = __builtin_amdgcn_readfirstlane(csr_src[i + j]);
#pragma unroll
        for (int j = 0; j < 16; ++j) c[j] = dsq[s[j]];
#pragma unroll
        for (int j = 0; j < 16; ++j)
            p[j] = *(const unsigned int*)&srcb[(size_t)s[j] * XB_COLS + lane * 2];
#pragma unroll
        for (int j = 0; j < 16; ++j) {
            ax += c[j] * bf2f(p[j] & 0xffffu);
            ay += c[j] * bf2f(p[j] >> 16);
        }
    }
    for (; i + 8 <= end; i += 8) {
        int s[8]; float c[8]; unsigned int p[8];
#pragma unroll
        for (int j = 0; j < 8; ++j) s[j] = __builtin_amdgcn_readfirstlane(csr_src[i + j]);
#pragma unroll
        for (int j = 0; j < 8; ++j) c[j] = dsq[s[j]];
#pragma unroll
        for (int j = 0; j < 8; ++j)
            p[j] = *(const unsigned int*)&srcb[(size_t)s[j] * XB_COLS + lane * 2];
#pragma unroll
        for (int j = 0; j < 8; ++j) {
            ax += c[j] * bf2f(p[j] & 0xffffu);
            ay += c[j] * bf2f(p[j] >> 16);
        }
    }
    for (; i + 4 <= end; i += 4) {
        int s[4]; float c[4]; unsigned int p[4];
#pragma unroll
        for (int j = 0; j < 4; ++j) s[j] = __builtin_amdgcn_readfirstlane(csr_src[i + j]);
#pragma unroll
        for (int j = 0; j < 4; ++j) c[j] = dsq[s[j]];
#pragma unroll
        for (int j = 0; j < 4; ++j)
            p[j] = *(const unsigned int*)&srcb[(size_t)s[j] * XB_COLS + lane * 2];
#pragma unroll
        for (int j = 0; j < 4; ++j) {
            ax += c[j] * bf2f(p[j] & 0xffffu);
            ay += c[j] * bf2f(p[j] >> 16);
        }
    }
    for (; i < end; ++i) {
        int s = __builtin_amdgcn_readfirstlane(csr_src[i]);
        float sc = dsq[s];
        unsigned int pv = *(const unsigned int*)&srcb[(size_t)s * XB_COLS + lane * 2];
        ax += sc * bf2f(pv & 0xffffu);
        ay += sc * bf2f(pv >> 16);
    }
    float ds = dsq[n];
    float a = (first ? -rn : -2.0f * rn) * ds;
    float b = first ? (rn - 1.0f) : 2.0f * (rn - 1.0f);
    unsigned int pu = *(const unsigned int*)&prevb[(size_t)n * XB_COLS + lane * 2];
    float rx = a * ax + b * bf2f(pu & 0xffffu);
    float ry = a * ay + b * bf2f(pu >> 16);
    if (ppb) {
        unsigned int qu = *(const unsigned int*)&ppb[(size_t)n * XB_COLS + lane * 2];
        rx -= bf2f(qu & 0xffffu);
        ry -= bf2f(qu >> 16);
    }
    unsigned int packed = (unsigned int)f2bf(rx) | ((unsigned int)f2bf(ry) << 16);
    *(unsigned int*)&outb[(size_t)n * XB_COLS + lane * 2] = packed;
}

// MFMA bf16 GEMM with fused BN column-stats (shfl + per-wave LDS, no LDS atomics)
__global__ __launch_bounds__(256) void k_gemm(const unsigned short* __restrict__ Xb,
                                              const unsigned short* __restrict__ Wt,
                                              const float* __restrict__ bias,
                                              float* __restrict__ out,
                                              float* __restrict__ colsum,
                                              float* __restrict__ colsq) {
    __shared__ unsigned short sA[128 * 32];
    __shared__ unsigned short sB[128 * 32];
    __shared__ float cs[4][OUT_F];
    __shared__ float cq[4][OUT_F];
    int tid = threadIdx.x;
    int wave = tid >> 6, lane = tid & 63;
    int quad = lane >> 4, m16 = lane & 15;
    int row0 = blockIdx.x * 128;

    floatx4 acc[2][8];
#pragma unroll
    for (int mt = 0; mt < 2; ++mt)
#pragma unroll
        for (int nt = 0; nt < 8; ++nt) acc[mt][nt] = (floatx4)(0.0f);

    int r  = tid >> 2;
    int c8 = (tid & 3) * 8;
    int gr0 = min(row0 + r, N_NODES - 1);
    int gr1 = min(row0 + r + 64, N_NODES - 1);

    for (int k0 = 0; k0 < 640; k0 += 32) {
        *(uint4*)&sA[r * 32 + c8]        = *(const uint4*)&Xb[(size_t)gr0 * XB_COLS + k0 + c8];
        *(uint4*)&sA[(r + 64) * 32 + c8] = *(const uint4*)&Xb[(size_t)gr1 * XB_COLS + k0 + c8];
        *(uint4*)&sB[r * 32 + c8]        = *(const uint4*)&Wt[r * 640 + k0 + c8];
        *(uint4*)&sB[(r + 64) * 32 + c8] = *(const uint4*)&Wt[(r + 64) * 640 + k0 + c8];
        __syncthreads();
        short8 a0 = *(short8*)&sA[(wave * 32 + m16) * 32 + quad * 8];
        short8 a1 = *(short8*)&sA[(wave * 32 + 16 + m16) * 32 + quad * 8];
#pragma unroll
        for (int nt = 0; nt < 8; ++nt) {
            short8 b = *(short8*)&sB[(nt * 16 + m16) * 32 + quad * 8];
            acc[0][nt] = __builtin_amdgcn_mfma_f32_16x16x32_bf16(a0, b, acc[0][nt], 0, 0, 0);
            acc[1][nt] = __builtin_amdgcn_mfma_f32_16x16x32_bf16(a1, b, acc[1][nt], 0, 0, 0);
        }
        __syncthreads();
    }
#pragma unroll
    for (int nt = 0; nt < 8; ++nt) {
        int col = nt * 16 + m16;
        float bb = bias[col];
        float sv = 0.0f, sq = 0.0f;
#pragma unroll
        for (int mt = 0; mt < 2; ++mt) {
            int rbase = row0 + wave * 32 + mt * 16 + quad * 4;
#pragma unroll
            for (int reg = 0; reg < 4; ++reg) {
                int row = rbase + reg;
                if (row < N_NODES) {
                    float w = acc[mt][nt][reg] + bb;
                    out[(size_t)row * OUT_F + col] = w;
                    sv += w;
                    sq += w * w;
                }
            }
        }
        sv += __shfl_down(sv, 32); sq += __shfl_down(sq, 32);
        sv += __shfl_down(sv, 16); sq += __shfl_down(sq, 16);
        if (lane < 16) { cs[wave][col] = sv; cq[wave][col] = sq; }
    }
    __syncthreads();
    if (tid < OUT_F) {
        float s = cs[0][tid] + cs[1][tid] + cs[2][tid] + cs[3][tid];
        float q = cq[0][tid] + cq[1][tid] + cq[2][tid] + cq[3][tid];
        atomicAdd(&colsum[tid], s);
        atomicAdd(&colsq[tid], q);
    }
}

__global__ void k_bn_apply(float* __restrict__ out, const float* __restrict__ colsum,
                           const float* __restrict__ colsq, const float* __restrict__ gamma,
                           const float* __restrict__ beta) {
    int t = blockIdx.x * 256 + threadIdx.x;
    int n = t >> 5, c = t & 31;
    float4 v = *(float4*)&out[n * OUT_F + c * 4];
    float4 s = *(const float4*)&colsum[c * 4];
    float4 q = *(const float4*)&colsq[c * 4];
    float4 g = *(const float4*)&gamma[c * 4];
    float4 b = *(const float4*)&beta[c * 4];
    const float invN = 1.0f / (float)N_NODES;
    float mux = s.x * invN, muy = s.y * invN, muz = s.z * invN, muw = s.w * invN;
    float ix = rsqrtf(q.x * invN - mux * mux + BN_EPSF);
    float iy = rsqrtf(q.y * invN - muy * muy + BN_EPSF);
    float iz = rsqrtf(q.z * invN - muz * muz + BN_EPSF);
    float iw = rsqrtf(q.w * invN - muw * muw + BN_EPSF);
    v.x = fmaxf(0.0f, (v.x - mux) * ix * g.x + b.x);
    v.y = fmaxf(0.0f, (v.y - muy) * iy * g.y + b.y);
    v.z = fmaxf(0.0f, (v.z - muz) * iz * g.z + b.z);
    v.w = fmaxf(0.0f, (v.w - muw) * iw * g.w + b.w);
    *(float4*)&out[n * OUT_F + c * 4] = v;
}

extern "C" void kernel_launch(void* const* d_in, const int* in_sizes, int n_in,
                              void* d_out, int out_size, void* d_ws, size_t ws_size,
                              hipStream_t stream) {
    const float* feature    = (const float*)d_in[0];
    const float* lin_w      = (const float*)d_in[1];
    const float* lin_b      = (const float*)d_in[2];
    const float* ew0        = (const float*)d_in[3];
    const float* eb0        = (const float*)d_in[4];
    const float* ew1        = (const float*)d_in[5];
    const float* eb1        = (const float*)d_in[6];
    const float* ew2        = (const float*)d_in[7];
    const float* eb2        = (const float*)d_in[8];
    const float* bn_gamma   = (const float*)d_in[9];
    const float* bn_beta    = (const float*)d_in[10];
    const float* lambda_max = (const float*)d_in[11];
    const float* evecs      = (const float*)d_in[12];
    const float* evals      = (const float*)d_in[13];
    const int*   edge_src   = (const int*)d_in[14];
    const int*   edge_dst   = (const int*)d_in[15];

    float* out = (float*)d_out;
    float* ws  = (float*)d_ws;
    unsigned short* Xb = (unsigned short*)(ws + OFF_XB);
    unsigned short* Wt = (unsigned short*)(ws + OFF_WT);
    float* dsq      = ws + OFF_DSQRT;
    float* hs_small = ws + OFF_HS;
    float* ef       = ws + OFF_EF;
    float* colsum   = ws + OFF_COLSUM;
    float* colsq    = ws + OFF_COLSQ;
    int*   degC     = (int*)(ws + OFF_DEGC);
    int*   rsC      = (int*)(ws + OFF_RSC);
    int*   row_start= (int*)(ws + OFF_ROWSTART);
    int*   csr_src  = (int*)(ws + OFF_CSR);
    int*   bsum     = (int*)(ws + OFF_BSUM);
    int*   rank     = (int*)(ws + OFF_RANK);
    float* partials = ws + OFF_X1F;

    // ---- prep (feat->bf16, W->Wt bf16, zero stats) ----
    k_prep<<<3479, 256, 0, stream>>>(feature, lin_w, Xb, Wt, hs_small);

    // ---- fused: hs_partial | eigen-MLP | LDS-rank (zero device atomics, 4-deep ILP) ----
    k_stage2<<<HSP_BLOCKS + 32 + RANKB, 256, 0, stream>>>(evecs, feature, partials,
                                                          evals, ew0, eb0, ew1, eb1, ew2, eb2,
                                                          ef, degC, edge_dst, rank);

    // ---- fused: scan1 | hs_reduce ----
    k_stage3<<<SCAN_BLK + 128, 1024, 0, stream>>>(degC, row_start, bsum, partials, hs_small);
    k_scan3<<<SCAN_BLK, 1024, 0, stream>>>(degC, row_start, bsum, dsq, rsC);

    // ---- fused: csr scatter | hs_apply ----
    k_stage6<<<3125 + 1563, 256, 0, stream>>>(edge_src, edge_dst, rank, rsC, csr_src,
                                              Xb, evecs, hs_small, ef);

    // ---- Chebyshev recurrence (all-bf16 state in Xb column slots) ----
    const int GBLK = (N_NODES * 64 + 255) / 256;
    k_gather<<<GBLK, 256, 0, stream>>>(row_start, csr_src, dsq,
                                       Xb + 0, Xb + 0, (const unsigned short*)nullptr,
                                       Xb + IN_F, lambda_max, 1);
    k_gather<<<GBLK, 256, 0, stream>>>(row_start, csr_src, dsq,
                                       Xb + IN_F, Xb + IN_F, Xb + 0,
                                       Xb + 2 * IN_F, lambda_max, 0);
    k_gather<<<GBLK, 256, 0, stream>>>(row_start, csr_src, dsq,
                                       Xb + 2 * IN_F, Xb + 2 * IN_F, Xb + IN_F,
                                       Xb + 3 * IN_F, lambda_max, 0);

    // ---- MFMA linear (+BN stats) + BN apply ----
    k_gemm<<<(N_NODES + 127) / 128, 256, 0, stream>>>(Xb, Wt, lin_b, out, colsum, colsq);
    k_bn_apply<<<(N_NODES * 32) / 256, 256, 0, stream>>>(out, colsum, colsq, bn_gamma, bn_beta);
}